// Round 8
// baseline (301.029 us; speedup 1.0000x reference)
//
#include <hip/hip_runtime.h>

// ---------------------------------------------------------------------------
// PairInteractionGrid: B=4,T=64,N=32,M=32,D=128
//   p = price@W_p + b_p ; v = liquid@W_v + b_v
//   z = p@W1a + v@W1b + (p*v)@W1c + |p-v|@W1d + b1
//   out = silu(z)@W2 + b2
// R12 = R11 with the compile fix: __builtin_nontemporal_store needs a true
// vector type, not HIP's float4 class -> use ext-vector f32x4 in epilogue.
// k2 W2-GEMM operand swap (A=w2 frag, B=h frag): C col=lane=m, reg=out-col
// -> 16 f32x4 NT stores per wave (was 64 scalar dwords). k0/k1 = R9.
// ---------------------------------------------------------------------------

typedef short  short8  __attribute__((ext_vector_type(8)));
typedef float  f32x4   __attribute__((ext_vector_type(4)));
typedef float  f32x16  __attribute__((ext_vector_type(16)));

#define DEV static __device__ __forceinline__

DEV unsigned short f2bf(float f) {   // round-nearest-even (k0/k1 only)
  unsigned u;
  __builtin_memcpy(&u, &f, 4);
  unsigned r = (u + 0x7FFFu + ((u >> 16) & 1u)) >> 16;
  return (unsigned short)r;
}
// pack two fp32 -> [bf16(fh) | bf16(fl)] by truncation: one v_perm_b32
DEV unsigned pk2(float fh, float fl) {
  return __builtin_amdgcn_perm(__float_as_uint(fh), __float_as_uint(fl), 0x07060302u);
}
DEV float lo16(unsigned u) { return __uint_as_float(u << 16); }
DEV float hi16(unsigned u) { return __uint_as_float(u & 0xFFFF0000u); }

// async 16B/lane global->LDS copy (wave-uniform base + lane*16 dest)
DEV void cp16(unsigned short* l, const unsigned short* g) {
  __builtin_amdgcn_global_load_lds(
      (const __attribute__((address_space(1))) unsigned int*)g,
      (__attribute__((address_space(3))) unsigned int*)l, 16, 0, 0);
}

union V8 { uint4 u; unsigned a[4]; short8 s; };

// ---------------------------------------------------------------------------
// k0: weight folding + fragment-order swizzles — R5/R9 known-good verbatim
// ---------------------------------------------------------------------------
__global__ void k0_prep(const float* __restrict__ Wp, const float* __restrict__ bp,
                        const float* __restrict__ Wv, const float* __restrict__ bv,
                        const float* __restrict__ W1, const float* __restrict__ b1,
                        const float* __restrict__ W2,
                        unsigned short* __restrict__ w1cd, unsigned short* __restrict__ w2sw,
                        unsigned short* __restrict__ wpsw, unsigned short* __restrict__ gpsw,
                        unsigned short* __restrict__ wvsw, unsigned short* __restrict__ gvsw,
                        float* __restrict__ c1) {
  int t = blockIdx.x * 256 + threadIdx.x;
  if (t < 32768) {                       // w1cd (32x32x16 B-frag, K=256)
    int j = t & 7, lane = (t >> 3) & 63, r2 = t >> 9;
    int ct = r2 & 3, kt = r2 >> 2;
    int k = kt * 16 + (lane >> 5) * 8 + j;
    int c = ct * 32 + (lane & 31);
    w1cd[t] = f2bf(W1[(256 + k) * 128 + c]);
  } else if (t < 114688) {
    int e = t - 32768;
    int sec = e >> 14;                   // 0:w2(32x32 frag) 1:wp 2:gp 3:wv 4:gv (16x16 frag)
    int f = e & 16383;
    int j = f & 7, lane = (f >> 3) & 63, r2 = f >> 9;
    if (sec == 0) {                      // 32x32x16 B-frag, K=128
      int ct = r2 & 3, kt = r2 >> 2;     // kt in [0,8)
      int k = kt * 16 + (lane >> 5) * 8 + j;
      int c = ct * 32 + (lane & 31);
      w2sw[f] = f2bf(W2[k * 128 + c]);
    } else {
      int kt = r2 & 3, ct = r2 >> 2;
      int k = kt * 32 + ((lane >> 4) & 3) * 8 + j;
      int n = ct * 16 + (lane & 15);
      if (sec == 1) {
        wpsw[f] = f2bf(Wp[k * 128 + n]);
      } else if (sec == 2) {
        float s = 0.f;
        for (int e2 = 0; e2 < 128; e2++) s += Wp[k * 128 + e2] * W1[e2 * 128 + n];
        gpsw[f] = f2bf(s);
      } else if (sec == 3) {
        wvsw[f] = f2bf(Wv[k * 128 + n]);
      } else {
        float s = 0.f;
        for (int e2 = 0; e2 < 128; e2++) s += Wv[k * 128 + e2] * W1[(128 + e2) * 128 + n];
        gvsw[f] = f2bf(s);
      }
    }
  } else if (t < 114816) {               // c1
    int c = t - 114688;
    float s = b1[c];
    for (int e2 = 0; e2 < 128; e2++)
      s += bp[e2] * W1[e2 * 128 + c] + bv[e2] * W1[(128 + e2) * 128 + c];
    c1[c] = s;
  }
}

// ---------------------------------------------------------------------------
// k1: projection GEMM. grid=512: b>>2 = 64-row chunk, b&3 = {side,half}.
// 2 blk/CU; FULL 32 KB B-frag table staged into LDS once per block.
// ---------------------------------------------------------------------------
__global__ __launch_bounds__(256, 2) void k1_proj(
    const float* __restrict__ price, const float* __restrict__ liquid,
    const float* __restrict__ bp, const float* __restrict__ bv, const float* __restrict__ c1,
    const unsigned short* __restrict__ wpsw, const unsigned short* __restrict__ gpsw,
    const unsigned short* __restrict__ wvsw, const unsigned short* __restrict__ gvsw,
    unsigned short* __restrict__ pbf, unsigned short* __restrict__ vbf,
    float* __restrict__ pAc, unsigned short* __restrict__ vbsw) {
  __shared__ __align__(16) unsigned short sA[64 * 136];   // 17.4 KB
  __shared__ __align__(16) unsigned short sB[16384];      // 32 KB (FULL table)
  int b = blockIdx.x;
  int chunk = b >> 2, sel = b & 3;
  int side = sel >> 1, half = sel & 1;
  int rowbase = chunk * 64;
  const float* src = side ? liquid : price;
  const unsigned short* bsw = side ? (half ? gvsw : wvsw) : (half ? gpsw : wpsw);
  int tid = threadIdx.x;

#pragma unroll
  for (int r = 0; r < 8; r++)             // stage B-frag table (32 KB)
    cp16(&sB[r * 2048 + tid * 8], bsw + r * 2048 + tid * 8);

#pragma unroll
  for (int i = 0; i < 8; i++) {           // stage A rows (64x128 f32 -> bf16)
    int e4 = i * 256 + tid;
    int row = e4 >> 5, c4 = (e4 & 31) * 4;
    float4 f = *(const float4*)(src + (rowbase + row) * 128 + c4);
    uint2 pk;
    pk.x = pk2(f.y, f.x);   // truncation is fine for GEMM inputs
    pk.y = pk2(f.w, f.z);
    *(uint2*)&sA[row * 136 + c4] = pk;
  }
  __syncthreads();

  int lane = tid & 63, w = tid >> 6;
  int l15 = lane & 15, q4 = lane >> 4;
  f32x4 acc[8] = {};
#pragma unroll
  for (int kt = 0; kt < 4; kt++) {
    short8 a0 = *(const short8*)&sA[(w * 16 + l15) * 136 + kt * 32 + q4 * 8];
#pragma unroll
    for (int ct = 0; ct < 8; ct++) {
      short8 bfr = *(const short8*)&sB[((ct * 4 + kt) * 64 + lane) * 8];
      acc[ct] = __builtin_amdgcn_mfma_f32_16x16x32_bf16(a0, bfr, acc[ct], 0, 0, 0);
    }
  }

#pragma unroll
  for (int ct = 0; ct < 8; ct++) {
    int col = ct * 16 + l15;
    int lrow0 = w * 16 + q4 * 4;
#pragma unroll
    for (int ri = 0; ri < 4; ri++) {
      int grow = rowbase + lrow0 + ri;
      float val = acc[ct][ri];
      if (side == 0) {
        if (half == 0) pbf[grow * 128 + col] = f2bf(val + bp[col]);
        else           pAc[grow * 128 + col] = val + c1[col];
      } else {
        if (half == 0) vbf[grow * 128 + col] = f2bf(val + bv[col]);
        else {
          int btl = grow >> 5, m = grow & 31;
          int idx = btl * 4096 +
                    ((((m >> 4) * 4 + (col >> 5)) * 64) + ((m >> 3) & 1) * 32 + (col & 31)) * 8 +
                    (m & 7);
          vbsw[idx] = f2bf(val);   // 32x32x16 B-frag order, K index = m
        }
      }
    }
  }
}

// ---------------------------------------------------------------------------
// k2_fused: pair stage + output GEMM. grid=2048. R9 + swapped W2 GEMM
// (A=w2 frag, B=h frag) -> vectorized f32x4 epilogue stores.
// ---------------------------------------------------------------------------
__global__ __launch_bounds__(256, 3) void k2_fused(
    const unsigned short* __restrict__ pbf, const unsigned short* __restrict__ vbf,
    const float* __restrict__ pAc, const unsigned short* __restrict__ w1cd,
    const unsigned short* __restrict__ vbsw, const unsigned short* __restrict__ w2sw,
    const float* __restrict__ b2, float* __restrict__ out) {
  __shared__ __align__(16) unsigned short sVf[4096];        // v in 32x32x16 A-frag order (8 KB)
  __shared__ __align__(16) unsigned short sP[4 * 136];      // p rows for this slab (1.1 KB)
  __shared__ __align__(16) unsigned short sHt[4][32 * 72];  // per-wave transpose buf (18.4 KB)
  __shared__ __align__(16) unsigned short sVb[4096];        // vbsw slab, B-frag order (8 KB)
  __shared__ __align__(16) unsigned short sT[8192];         // w1cd kt-slice dbuf 2x8KB (16 KB)
  int bt = blockIdx.x >> 3, slab = (blockIdx.x & 7) * 4;
  int tid = threadIdx.x;
  const unsigned short* vbswt = vbsw + bt * 4096;

  // async table stages: w1cd kt=0 slice (x half + y half) and vbsw slab
  cp16(&sT[tid * 8],        w1cd + tid * 8);                 // x, kt=0
  cp16(&sT[2048 + tid * 8], w1cd + 16384 + tid * 8);         // y, kt=0
  cp16(&sVb[tid * 8],        vbswt + tid * 8);
  cp16(&sVb[2048 + tid * 8], vbswt + 2048 + tid * 8);

  if (tid < 64) {  // stage p (4 rows)
    int row = tid >> 4, seg = tid & 15;
    *(uint4*)&sP[row * 136 + seg * 8] = *(const uint4*)(pbf + (bt * 32 + slab + row) * 128 + seg * 8);
  }
#pragma unroll
  for (int g2 = 0; g2 < 2; g2++) {  // stage v in A-frag order: ((kt*2+hi)*32+m)*8+j
    int g = tid * 2 + g2;
    int m = g & 31, k0 = (g >> 5) * 8;
    *(uint4*)&sVf[g * 8] = *(const uint4*)(vbf + (bt * 32 + m) * 128 + k0);
  }
  __syncthreads();

  int lane = tid & 63, w = tid >> 6;
  int m31 = lane & 31, hi = lane >> 5;
  int n = slab + w;                 // this wave's n row

  // per-lane constants: pAc row (per ct col-block)
  float pa[4];
#pragma unroll
  for (int ct = 0; ct < 4; ct++)
    pa[ct] = pAc[(bt * 32 + n) * 128 + ct * 32 + m31];

  f32x16 acc[4] = {};

#pragma unroll
  for (int kt = 0; kt < 8; kt++) {  // K=128 over x=(p*v) and y=|p-v| together
    const unsigned short* bcur = sT + (kt & 1) * 4096;
    if (kt < 7) {                   // 2-phase: issue next kt slice while computing
      unsigned short* bnx = sT + ((kt + 1) & 1) * 4096;
      cp16(&bnx[tid * 8],        w1cd + (kt + 1) * 2048 + tid * 8);
      cp16(&bnx[2048 + tid * 8], w1cd + (kt + 9) * 2048 + tid * 8);
    }
    V8 vf, pp, x, y;
    vf.u = *(const uint4*)&sVf[((kt * 2 + hi) * 32 + m31) * 8];
    pp.u = *(const uint4*)&sP[w * 136 + kt * 16 + hi * 8];
#pragma unroll
    for (int i = 0; i < 4; i++) {
      float vl = lo16(vf.a[i]), vh = hi16(vf.a[i]);
      float al = lo16(pp.a[i]), ah = hi16(pp.a[i]);
      x.a[i] = pk2(ah * vh, al * vl);
      y.a[i] = pk2(fabsf(ah - vh), fabsf(al - vl));
    }
#pragma unroll
    for (int ct = 0; ct < 4; ct++) {
      short8 bx = *(const short8*)(bcur + ct * 512 + lane * 8);
      short8 by = *(const short8*)(bcur + 2048 + ct * 512 + lane * 8);
      acc[ct] = __builtin_amdgcn_mfma_f32_32x32x16_bf16(x.s, bx, acc[ct], 0, 0, 0);
      acc[ct] = __builtin_amdgcn_mfma_f32_32x32x16_bf16(y.s, by, acc[ct], 0, 0, 0);
    }
    __syncthreads();                // stage kt+1 done; all waves done with bcur
  }

  // stage w2 p0 slice (16 KB) into the now-dead sT
#pragma unroll
  for (int r = 0; r < 4; r++)
    cp16(&sT[r * 2048 + tid * 8], w2sw + r * 2048 + tid * 8);

  // vB via indicator GEMM: A[r][k]=delta(r==k), B=vB (frag order), K=32
#pragma unroll
  for (int kt2 = 0; kt2 < 2; kt2++) {
    short8 indf;
#pragma unroll
    for (int j = 0; j < 8; j++)
      indf[j] = (short)(((kt2 * 16 + hi * 8 + j) == m31) ? 0x3F80 : 0);
#pragma unroll
    for (int ct = 0; ct < 4; ct++) {
      short8 bi = *(const short8*)(sVb + (kt2 * 4 + ct) * 512 + lane * 8);
      acc[ct] = __builtin_amdgcn_mfma_f32_32x32x16_bf16(indf, bi, acc[ct], 0, 0, 0);
    }
  }
  __syncthreads();                  // w2 p0 stage complete

  // silu (pAc folded) -> per-wave LDS transpose -> out via swapped-operand
  // W2 GEMM: o = mfma(A=w2frag, B=hfrag); C col=lane=m, reg=out-col.
  unsigned short* sh = &sHt[w][0];
  f32x16 o[4] = {};
#pragma unroll
  for (int p = 0; p < 2; p++) {
    if (p == 0) {                   // stage w2 p1 slice into dead sVf+sVb
#pragma unroll
      for (int r = 0; r < 4; r++)
        cp16(r < 2 ? &sVf[r * 2048 + tid * 8] : &sVb[(r - 2) * 2048 + tid * 8],
             w2sw + 8192 + r * 2048 + tid * 8);
    }
#pragma unroll
    for (int c2 = 0; c2 < 2; c2++) {
      int ct = p * 2 + c2;
#pragma unroll
      for (int reg = 0; reg < 16; reg++) {
        float z = acc[ct][reg] + pa[ct];
        float hv = z * __builtin_amdgcn_rcpf(1.f + __expf(-z));
        int mr = (reg & 3) + 8 * (reg >> 2) + 4 * hi;   // C-layout row = pair m
        sh[mr * 72 + c2 * 32 + m31] = (unsigned short)(__float_as_uint(hv) >> 16);
      }
    }
#pragma unroll
    for (int kt = 0; kt < 4; kt++) {
      short8 hf = *(const short8*)&sh[m31 * 72 + kt * 16 + hi * 8];
#pragma unroll
      for (int ct2 = 0; ct2 < 4; ct2++) {
        int idx = (kt * 4 + ct2) * 512 + lane * 8;      // shorts, within 16KB slice
        const unsigned short* wsrc;
        if (p == 0)       wsrc = sT + idx;
        else if (kt < 2)  wsrc = sVf + idx;
        else              wsrc = sVb + idx - 4096;
        short8 wf = *(const short8*)wsrc;
        o[ct2] = __builtin_amdgcn_mfma_f32_32x32x16_bf16(wf, hf, o[ct2], 0, 0, 0);
      }
    }
    if (p == 0) __syncthreads();    // w2 p1 stage complete before p=1 reads
  }

  // epilogue: lane m31 owns out row (rowb+m31); reg quad = 4 consecutive cols
  int orow = (bt * 1024 + n * 32 + m31) * 128;
#pragma unroll
  for (int ct2 = 0; ct2 < 4; ct2++) {
#pragma unroll
    for (int g = 0; g < 4; g++) {
      int cbase = ct2 * 32 + g * 8 + hi * 4;            // col = cbase + (reg&3)
      f32x4 bb = *(const f32x4*)(b2 + cbase);
      f32x4 vv;
      vv[0] = o[ct2][g * 4 + 0] + bb[0];
      vv[1] = o[ct2][g * 4 + 1] + bb[1];
      vv[2] = o[ct2][g * 4 + 2] + bb[2];
      vv[3] = o[ct2][g * 4 + 3] + bb[3];
      __builtin_nontemporal_store(vv, (f32x4*)(out + orow + cbase));
    }
  }
}

// ---------------------------------------------------------------------------
extern "C" void kernel_launch(void* const* d_in, const int* in_sizes, int n_in,
                              void* d_out, int out_size, void* d_ws, size_t ws_size,
                              hipStream_t stream) {
  const float* price  = (const float*)d_in[0];
  const float* liquid = (const float*)d_in[1];
  const float* Wp     = (const float*)d_in[2];
  const float* bp     = (const float*)d_in[3];
  const float* Wv     = (const float*)d_in[4];
  const float* bv     = (const float*)d_in[5];
  const float* W1     = (const float*)d_in[6];
  const float* b1     = (const float*)d_in[7];
  const float* W2     = (const float*)d_in[8];
  const float* b2     = (const float*)d_in[9];

  char* ws = (char*)d_ws;
  unsigned short* w1cd = (unsigned short*)(ws + 0);         //  64 KB
  unsigned short* w2sw = (unsigned short*)(ws + 65536);     //  32 KB
  unsigned short* wpsw = (unsigned short*)(ws + 98304);     //  32 KB
  unsigned short* gpsw = (unsigned short*)(ws + 131072);    //  32 KB
  unsigned short* wvsw = (unsigned short*)(ws + 163840);    //  32 KB
  unsigned short* gvsw = (unsigned short*)(ws + 196608);    //  32 KB
  float*          c1   = (float*)(ws + 229376);             // 512 B
  unsigned short* pbf  = (unsigned short*)(ws + 262144);    //   2 MB
  unsigned short* vbf  = (unsigned short*)(ws + 2359296);   //   2 MB
  float*          pAc  = (float*)(ws + 4456448);            //   4 MB
  unsigned short* vbsw = (unsigned short*)(ws + 8650752);   //   2 MB -> total ~10.3 MB

  hipLaunchKernelGGL(k0_prep, dim3(449), dim3(256), 0, stream,
                     Wp, bp, Wv, bv, W1, b1, W2, w1cd, w2sw, wpsw, gpsw, wvsw, gvsw, c1);
  hipLaunchKernelGGL(k1_proj, dim3(512), dim3(256), 0, stream,
                     price, liquid, bp, bv, c1, wpsw, gpsw, wvsw, gvsw, pbf, vbf, pAc, vbsw);
  hipLaunchKernelGGL(k2_fused, dim3(2048), dim3(256), 0, stream,
                     pbf, vbf, pAc, w1cd, vbsw, w2sw, b2, (float*)d_out);
}

// Round 9
// 200.833 us; speedup vs baseline: 1.4989x; 1.4989x over previous
//
#include <hip/hip_runtime.h>

// ---------------------------------------------------------------------------
// PairInteractionGrid: B=4,T=64,N=32,M=32,D=128
//   p = price@W_p + b_p ; v = liquid@W_v + b_v
//   z = p@W1a + v@W1b + (p*v)@W1c + |p-v|@W1d + b1
//   out = silu(z)@W2 + b2
// R13 = exact revert to R9 (198.4us known-good). R12's swapped-operand
// epilogue wrote 16B/lane at 512B row stride -> 32B segments, 2x write
// amplification (WRITE_SIZE 256MB vs 134MB output), k2 57->160us.
// R9's epilogue: C col=lane -> 64 coalesced scalar dword NT stores (256B
// contiguous per instruction). Keep.
// ---------------------------------------------------------------------------

typedef short  short8  __attribute__((ext_vector_type(8)));
typedef float  f32x4   __attribute__((ext_vector_type(4)));
typedef float  f32x16  __attribute__((ext_vector_type(16)));

#define DEV static __device__ __forceinline__

DEV unsigned short f2bf(float f) {   // round-nearest-even (k0/k1 only)
  unsigned u;
  __builtin_memcpy(&u, &f, 4);
  unsigned r = (u + 0x7FFFu + ((u >> 16) & 1u)) >> 16;
  return (unsigned short)r;
}
// pack two fp32 -> [bf16(fh) | bf16(fl)] by truncation: one v_perm_b32
DEV unsigned pk2(float fh, float fl) {
  return __builtin_amdgcn_perm(__float_as_uint(fh), __float_as_uint(fl), 0x07060302u);
}
DEV float lo16(unsigned u) { return __uint_as_float(u << 16); }
DEV float hi16(unsigned u) { return __uint_as_float(u & 0xFFFF0000u); }

// async 16B/lane global->LDS copy (wave-uniform base + lane*16 dest)
DEV void cp16(unsigned short* l, const unsigned short* g) {
  __builtin_amdgcn_global_load_lds(
      (const __attribute__((address_space(1))) unsigned int*)g,
      (__attribute__((address_space(3))) unsigned int*)l, 16, 0, 0);
}

union V8 { uint4 u; unsigned a[4]; short8 s; };

// ---------------------------------------------------------------------------
// k0: weight folding + fragment-order swizzles — R5/R9 known-good verbatim
// ---------------------------------------------------------------------------
__global__ void k0_prep(const float* __restrict__ Wp, const float* __restrict__ bp,
                        const float* __restrict__ Wv, const float* __restrict__ bv,
                        const float* __restrict__ W1, const float* __restrict__ b1,
                        const float* __restrict__ W2,
                        unsigned short* __restrict__ w1cd, unsigned short* __restrict__ w2sw,
                        unsigned short* __restrict__ wpsw, unsigned short* __restrict__ gpsw,
                        unsigned short* __restrict__ wvsw, unsigned short* __restrict__ gvsw,
                        float* __restrict__ c1) {
  int t = blockIdx.x * 256 + threadIdx.x;
  if (t < 32768) {                       // w1cd (32x32x16 B-frag, K=256)
    int j = t & 7, lane = (t >> 3) & 63, r2 = t >> 9;
    int ct = r2 & 3, kt = r2 >> 2;
    int k = kt * 16 + (lane >> 5) * 8 + j;
    int c = ct * 32 + (lane & 31);
    w1cd[t] = f2bf(W1[(256 + k) * 128 + c]);
  } else if (t < 114688) {
    int e = t - 32768;
    int sec = e >> 14;                   // 0:w2(32x32 frag) 1:wp 2:gp 3:wv 4:gv (16x16 frag)
    int f = e & 16383;
    int j = f & 7, lane = (f >> 3) & 63, r2 = f >> 9;
    if (sec == 0) {                      // 32x32x16 B-frag, K=128
      int ct = r2 & 3, kt = r2 >> 2;     // kt in [0,8)
      int k = kt * 16 + (lane >> 5) * 8 + j;
      int c = ct * 32 + (lane & 31);
      w2sw[f] = f2bf(W2[k * 128 + c]);
    } else {
      int kt = r2 & 3, ct = r2 >> 2;
      int k = kt * 32 + ((lane >> 4) & 3) * 8 + j;
      int n = ct * 16 + (lane & 15);
      if (sec == 1) {
        wpsw[f] = f2bf(Wp[k * 128 + n]);
      } else if (sec == 2) {
        float s = 0.f;
        for (int e2 = 0; e2 < 128; e2++) s += Wp[k * 128 + e2] * W1[e2 * 128 + n];
        gpsw[f] = f2bf(s);
      } else if (sec == 3) {
        wvsw[f] = f2bf(Wv[k * 128 + n]);
      } else {
        float s = 0.f;
        for (int e2 = 0; e2 < 128; e2++) s += Wv[k * 128 + e2] * W1[(128 + e2) * 128 + n];
        gvsw[f] = f2bf(s);
      }
    }
  } else if (t < 114816) {               // c1
    int c = t - 114688;
    float s = b1[c];
    for (int e2 = 0; e2 < 128; e2++)
      s += bp[e2] * W1[e2 * 128 + c] + bv[e2] * W1[(128 + e2) * 128 + c];
    c1[c] = s;
  }
}

// ---------------------------------------------------------------------------
// k1: projection GEMM. grid=512: b>>2 = 64-row chunk, b&3 = {side,half}.
// 2 blk/CU; FULL 32 KB B-frag table staged into LDS once per block.
// ---------------------------------------------------------------------------
__global__ __launch_bounds__(256, 2) void k1_proj(
    const float* __restrict__ price, const float* __restrict__ liquid,
    const float* __restrict__ bp, const float* __restrict__ bv, const float* __restrict__ c1,
    const unsigned short* __restrict__ wpsw, const unsigned short* __restrict__ gpsw,
    const unsigned short* __restrict__ wvsw, const unsigned short* __restrict__ gvsw,
    unsigned short* __restrict__ pbf, unsigned short* __restrict__ vbf,
    float* __restrict__ pAc, unsigned short* __restrict__ vbsw) {
  __shared__ __align__(16) unsigned short sA[64 * 136];   // 17.4 KB
  __shared__ __align__(16) unsigned short sB[16384];      // 32 KB (FULL table)
  int b = blockIdx.x;
  int chunk = b >> 2, sel = b & 3;
  int side = sel >> 1, half = sel & 1;
  int rowbase = chunk * 64;
  const float* src = side ? liquid : price;
  const unsigned short* bsw = side ? (half ? gvsw : wvsw) : (half ? gpsw : wpsw);
  int tid = threadIdx.x;

#pragma unroll
  for (int r = 0; r < 8; r++)             // stage B-frag table (32 KB)
    cp16(&sB[r * 2048 + tid * 8], bsw + r * 2048 + tid * 8);

#pragma unroll
  for (int i = 0; i < 8; i++) {           // stage A rows (64x128 f32 -> bf16)
    int e4 = i * 256 + tid;
    int row = e4 >> 5, c4 = (e4 & 31) * 4;
    float4 f = *(const float4*)(src + (rowbase + row) * 128 + c4);
    uint2 pk;
    pk.x = pk2(f.y, f.x);   // truncation is fine for GEMM inputs
    pk.y = pk2(f.w, f.z);
    *(uint2*)&sA[row * 136 + c4] = pk;
  }
  __syncthreads();

  int lane = tid & 63, w = tid >> 6;
  int l15 = lane & 15, q4 = lane >> 4;
  f32x4 acc[8] = {};
#pragma unroll
  for (int kt = 0; kt < 4; kt++) {
    short8 a0 = *(const short8*)&sA[(w * 16 + l15) * 136 + kt * 32 + q4 * 8];
#pragma unroll
    for (int ct = 0; ct < 8; ct++) {
      short8 bfr = *(const short8*)&sB[((ct * 4 + kt) * 64 + lane) * 8];
      acc[ct] = __builtin_amdgcn_mfma_f32_16x16x32_bf16(a0, bfr, acc[ct], 0, 0, 0);
    }
  }

#pragma unroll
  for (int ct = 0; ct < 8; ct++) {
    int col = ct * 16 + l15;
    int lrow0 = w * 16 + q4 * 4;
#pragma unroll
    for (int ri = 0; ri < 4; ri++) {
      int grow = rowbase + lrow0 + ri;
      float val = acc[ct][ri];
      if (side == 0) {
        if (half == 0) pbf[grow * 128 + col] = f2bf(val + bp[col]);
        else           pAc[grow * 128 + col] = val + c1[col];
      } else {
        if (half == 0) vbf[grow * 128 + col] = f2bf(val + bv[col]);
        else {
          int btl = grow >> 5, m = grow & 31;
          int idx = btl * 4096 +
                    ((((m >> 4) * 4 + (col >> 5)) * 64) + ((m >> 3) & 1) * 32 + (col & 31)) * 8 +
                    (m & 7);
          vbsw[idx] = f2bf(val);   // 32x32x16 B-frag order, K index = m
        }
      }
    }
  }
}

// ---------------------------------------------------------------------------
// k2_fused: pair stage + output GEMM. grid=2048. R9 verbatim.
// ---------------------------------------------------------------------------
__global__ __launch_bounds__(256, 3) void k2_fused(
    const unsigned short* __restrict__ pbf, const unsigned short* __restrict__ vbf,
    const float* __restrict__ pAc, const unsigned short* __restrict__ w1cd,
    const unsigned short* __restrict__ vbsw, const unsigned short* __restrict__ w2sw,
    const float* __restrict__ b2, float* __restrict__ out) {
  __shared__ __align__(16) unsigned short sVf[4096];        // v in 32x32x16 A-frag order (8 KB)
  __shared__ __align__(16) unsigned short sP[4 * 136];      // p rows for this slab (1.1 KB)
  __shared__ __align__(16) unsigned short sHt[4][32 * 72];  // per-wave transpose buf (18.4 KB)
  __shared__ __align__(16) unsigned short sVb[4096];        // vbsw slab, B-frag order (8 KB)
  __shared__ __align__(16) unsigned short sT[8192];         // w1cd kt-slice dbuf 2x8KB (16 KB)
  int bt = blockIdx.x >> 3, slab = (blockIdx.x & 7) * 4;
  int tid = threadIdx.x;
  const unsigned short* vbswt = vbsw + bt * 4096;

  // async table stages: w1cd kt=0 slice (x half + y half) and vbsw slab
  cp16(&sT[tid * 8],        w1cd + tid * 8);                 // x, kt=0
  cp16(&sT[2048 + tid * 8], w1cd + 16384 + tid * 8);         // y, kt=0
  cp16(&sVb[tid * 8],        vbswt + tid * 8);
  cp16(&sVb[2048 + tid * 8], vbswt + 2048 + tid * 8);

  if (tid < 64) {  // stage p (4 rows)
    int row = tid >> 4, seg = tid & 15;
    *(uint4*)&sP[row * 136 + seg * 8] = *(const uint4*)(pbf + (bt * 32 + slab + row) * 128 + seg * 8);
  }
#pragma unroll
  for (int g2 = 0; g2 < 2; g2++) {  // stage v in A-frag order: ((kt*2+hi)*32+m)*8+j
    int g = tid * 2 + g2;
    int m = g & 31, k0 = (g >> 5) * 8;
    *(uint4*)&sVf[g * 8] = *(const uint4*)(vbf + (bt * 32 + m) * 128 + k0);
  }
  __syncthreads();

  int lane = tid & 63, w = tid >> 6;
  int m31 = lane & 31, hi = lane >> 5;
  int n = slab + w;                 // this wave's n row

  // per-lane constants: pAc row (per ct col-block), b2 bias
  float pa[4], bia[4];
#pragma unroll
  for (int ct = 0; ct < 4; ct++) {
    pa[ct]  = pAc[(bt * 32 + n) * 128 + ct * 32 + m31];
    bia[ct] = b2[ct * 32 + m31];
  }

  f32x16 acc[4] = {};

#pragma unroll
  for (int kt = 0; kt < 8; kt++) {  // K=128 over x=(p*v) and y=|p-v| together
    const unsigned short* bcur = sT + (kt & 1) * 4096;
    if (kt < 7) {                   // 2-phase: issue next kt slice while computing
      unsigned short* bnx = sT + ((kt + 1) & 1) * 4096;
      cp16(&bnx[tid * 8],        w1cd + (kt + 1) * 2048 + tid * 8);
      cp16(&bnx[2048 + tid * 8], w1cd + (kt + 9) * 2048 + tid * 8);
    }
    V8 vf, pp, x, y;
    vf.u = *(const uint4*)&sVf[((kt * 2 + hi) * 32 + m31) * 8];
    pp.u = *(const uint4*)&sP[w * 136 + kt * 16 + hi * 8];
#pragma unroll
    for (int i = 0; i < 4; i++) {
      float vl = lo16(vf.a[i]), vh = hi16(vf.a[i]);
      float al = lo16(pp.a[i]), ah = hi16(pp.a[i]);
      x.a[i] = pk2(ah * vh, al * vl);
      y.a[i] = pk2(fabsf(ah - vh), fabsf(al - vl));
    }
#pragma unroll
    for (int ct = 0; ct < 4; ct++) {
      short8 bx = *(const short8*)(bcur + ct * 512 + lane * 8);
      short8 by = *(const short8*)(bcur + 2048 + ct * 512 + lane * 8);
      acc[ct] = __builtin_amdgcn_mfma_f32_32x32x16_bf16(x.s, bx, acc[ct], 0, 0, 0);
      acc[ct] = __builtin_amdgcn_mfma_f32_32x32x16_bf16(y.s, by, acc[ct], 0, 0, 0);
    }
    __syncthreads();                // stage kt+1 done; all waves done with bcur
  }

  // stage w2 p0 slice (16 KB) into the now-dead sT
#pragma unroll
  for (int r = 0; r < 4; r++)
    cp16(&sT[r * 2048 + tid * 8], w2sw + r * 2048 + tid * 8);

  // vB via indicator GEMM: A[r][k]=delta(r==k), B=vB (frag order), K=32
#pragma unroll
  for (int kt2 = 0; kt2 < 2; kt2++) {
    short8 indf;
#pragma unroll
    for (int j = 0; j < 8; j++)
      indf[j] = (short)(((kt2 * 16 + hi * 8 + j) == m31) ? 0x3F80 : 0);
#pragma unroll
    for (int ct = 0; ct < 4; ct++) {
      short8 bi = *(const short8*)(sVb + (kt2 * 4 + ct) * 512 + lane * 8);
      acc[ct] = __builtin_amdgcn_mfma_f32_32x32x16_bf16(indf, bi, acc[ct], 0, 0, 0);
    }
  }
  __syncthreads();                  // w2 p0 stage complete

  // silu (pAc folded) -> 2-pass LDS transpose (32x72, per-wave) -> h@W2+b2
  unsigned short* sh = &sHt[w][0];
  f32x16 o[4] = {};
#pragma unroll
  for (int p = 0; p < 2; p++) {
    if (p == 0) {                   // stage w2 p1 slice into dead sVf+sVb
#pragma unroll
      for (int r = 0; r < 4; r++)
        cp16(r < 2 ? &sVf[r * 2048 + tid * 8] : &sVb[(r - 2) * 2048 + tid * 8],
             w2sw + 8192 + r * 2048 + tid * 8);
    }
#pragma unroll
    for (int c2 = 0; c2 < 2; c2++) {
      int ct = p * 2 + c2;
#pragma unroll
      for (int reg = 0; reg < 16; reg++) {
        float z = acc[ct][reg] + pa[ct];
        float hv = z * __builtin_amdgcn_rcpf(1.f + __expf(-z));
        int mr = (reg & 3) + 8 * (reg >> 2) + 4 * hi;   // C-layout row = pair m
        sh[mr * 72 + c2 * 32 + m31] = (unsigned short)(__float_as_uint(hv) >> 16);
      }
    }
#pragma unroll
    for (int kt = 0; kt < 4; kt++) {
      short8 hf = *(const short8*)&sh[m31 * 72 + kt * 16 + hi * 8];
#pragma unroll
      for (int ct2 = 0; ct2 < 4; ct2++) {
        int idx = (kt * 4 + ct2) * 512 + lane * 8;      // shorts, within 16KB slice
        const unsigned short* wsrc;
        if (p == 0)       wsrc = sT + idx;
        else if (kt < 2)  wsrc = sVf + idx;
        else              wsrc = sVb + idx - 4096;
        short8 wf = *(const short8*)wsrc;
        o[ct2] = __builtin_amdgcn_mfma_f32_32x32x16_bf16(hf, wf, o[ct2], 0, 0, 0);
      }
    }
    if (p == 0) __syncthreads();    // w2 p1 stage complete before p=1 reads
  }

  int rowb = bt * 1024 + n * 32;
#pragma unroll
  for (int ct2 = 0; ct2 < 4; ct2++) {
#pragma unroll
    for (int reg = 0; reg < 16; reg++) {
      int mr = (reg & 3) + 8 * (reg >> 2) + 4 * hi;
      __builtin_nontemporal_store(o[ct2][reg] + bia[ct2],
                                  &out[(rowb + mr) * 128 + ct2 * 32 + m31]);
    }
  }
}

// ---------------------------------------------------------------------------
extern "C" void kernel_launch(void* const* d_in, const int* in_sizes, int n_in,
                              void* d_out, int out_size, void* d_ws, size_t ws_size,
                              hipStream_t stream) {
  const float* price  = (const float*)d_in[0];
  const float* liquid = (const float*)d_in[1];
  const float* Wp     = (const float*)d_in[2];
  const float* bp     = (const float*)d_in[3];
  const float* Wv     = (const float*)d_in[4];
  const float* bv     = (const float*)d_in[5];
  const float* W1     = (const float*)d_in[6];
  const float* b1     = (const float*)d_in[7];
  const float* W2     = (const float*)d_in[8];
  const float* b2     = (const float*)d_in[9];

  char* ws = (char*)d_ws;
  unsigned short* w1cd = (unsigned short*)(ws + 0);         //  64 KB
  unsigned short* w2sw = (unsigned short*)(ws + 65536);     //  32 KB
  unsigned short* wpsw = (unsigned short*)(ws + 98304);     //  32 KB
  unsigned short* gpsw = (unsigned short*)(ws + 131072);    //  32 KB
  unsigned short* wvsw = (unsigned short*)(ws + 163840);    //  32 KB
  unsigned short* gvsw = (unsigned short*)(ws + 196608);    //  32 KB
  float*          c1   = (float*)(ws + 229376);             // 512 B
  unsigned short* pbf  = (unsigned short*)(ws + 262144);    //   2 MB
  unsigned short* vbf  = (unsigned short*)(ws + 2359296);   //   2 MB
  float*          pAc  = (float*)(ws + 4456448);            //   4 MB
  unsigned short* vbsw = (unsigned short*)(ws + 8650752);   //   2 MB -> total ~10.3 MB

  hipLaunchKernelGGL(k0_prep, dim3(449), dim3(256), 0, stream,
                     Wp, bp, Wv, bv, W1, b1, W2, w1cd, w2sw, wpsw, gpsw, wvsw, gvsw, c1);
  hipLaunchKernelGGL(k1_proj, dim3(512), dim3(256), 0, stream,
                     price, liquid, bp, bv, c1, wpsw, gpsw, wvsw, gvsw, pbf, vbf, pAc, vbsw);
  hipLaunchKernelGGL(k2_fused, dim3(2048), dim3(256), 0, stream,
                     pbf, vbf, pAc, w1cd, vbsw, w2sw, b2, (float*)d_out);
}

// Round 10
// 197.825 us; speedup vs baseline: 1.5217x; 1.0152x over previous
//
#include <hip/hip_runtime.h>

// ---------------------------------------------------------------------------
// PairInteractionGrid: B=4,T=64,N=32,M=32,D=128
//   p = price@W_p + b_p ; v = liquid@W_v + b_v
//   z = p@W1a + v@W1b + (p*v)@W1c + |p-v|@W1d + b1
//   out = silu(z)@W2 + b2
// R14 = R13 (known-good 200.8us) with ONE change: k2 epilogue stores are
// plain (not nontemporal). R12's counters showed NT+scattered achieving
// 1.76 TB/s vs fills' 6.3 TB/s with plain stores; hypothesis: NT caps the
// streaming-write efficiency of the (coalesced) epilogue too.
// ---------------------------------------------------------------------------

typedef short  short8  __attribute__((ext_vector_type(8)));
typedef float  f32x4   __attribute__((ext_vector_type(4)));
typedef float  f32x16  __attribute__((ext_vector_type(16)));

#define DEV static __device__ __forceinline__

DEV unsigned short f2bf(float f) {   // round-nearest-even (k0/k1 only)
  unsigned u;
  __builtin_memcpy(&u, &f, 4);
  unsigned r = (u + 0x7FFFu + ((u >> 16) & 1u)) >> 16;
  return (unsigned short)r;
}
// pack two fp32 -> [bf16(fh) | bf16(fl)] by truncation: one v_perm_b32
DEV unsigned pk2(float fh, float fl) {
  return __builtin_amdgcn_perm(__float_as_uint(fh), __float_as_uint(fl), 0x07060302u);
}
DEV float lo16(unsigned u) { return __uint_as_float(u << 16); }
DEV float hi16(unsigned u) { return __uint_as_float(u & 0xFFFF0000u); }

// async 16B/lane global->LDS copy (wave-uniform base + lane*16 dest)
DEV void cp16(unsigned short* l, const unsigned short* g) {
  __builtin_amdgcn_global_load_lds(
      (const __attribute__((address_space(1))) unsigned int*)g,
      (__attribute__((address_space(3))) unsigned int*)l, 16, 0, 0);
}

union V8 { uint4 u; unsigned a[4]; short8 s; };

// ---------------------------------------------------------------------------
// k0: weight folding + fragment-order swizzles — R5/R9 known-good verbatim
// ---------------------------------------------------------------------------
__global__ void k0_prep(const float* __restrict__ Wp, const float* __restrict__ bp,
                        const float* __restrict__ Wv, const float* __restrict__ bv,
                        const float* __restrict__ W1, const float* __restrict__ b1,
                        const float* __restrict__ W2,
                        unsigned short* __restrict__ w1cd, unsigned short* __restrict__ w2sw,
                        unsigned short* __restrict__ wpsw, unsigned short* __restrict__ gpsw,
                        unsigned short* __restrict__ wvsw, unsigned short* __restrict__ gvsw,
                        float* __restrict__ c1) {
  int t = blockIdx.x * 256 + threadIdx.x;
  if (t < 32768) {                       // w1cd (32x32x16 B-frag, K=256)
    int j = t & 7, lane = (t >> 3) & 63, r2 = t >> 9;
    int ct = r2 & 3, kt = r2 >> 2;
    int k = kt * 16 + (lane >> 5) * 8 + j;
    int c = ct * 32 + (lane & 31);
    w1cd[t] = f2bf(W1[(256 + k) * 128 + c]);
  } else if (t < 114688) {
    int e = t - 32768;
    int sec = e >> 14;                   // 0:w2(32x32 frag) 1:wp 2:gp 3:wv 4:gv (16x16 frag)
    int f = e & 16383;
    int j = f & 7, lane = (f >> 3) & 63, r2 = f >> 9;
    if (sec == 0) {                      // 32x32x16 B-frag, K=128
      int ct = r2 & 3, kt = r2 >> 2;     // kt in [0,8)
      int k = kt * 16 + (lane >> 5) * 8 + j;
      int c = ct * 32 + (lane & 31);
      w2sw[f] = f2bf(W2[k * 128 + c]);
    } else {
      int kt = r2 & 3, ct = r2 >> 2;
      int k = kt * 32 + ((lane >> 4) & 3) * 8 + j;
      int n = ct * 16 + (lane & 15);
      if (sec == 1) {
        wpsw[f] = f2bf(Wp[k * 128 + n]);
      } else if (sec == 2) {
        float s = 0.f;
        for (int e2 = 0; e2 < 128; e2++) s += Wp[k * 128 + e2] * W1[e2 * 128 + n];
        gpsw[f] = f2bf(s);
      } else if (sec == 3) {
        wvsw[f] = f2bf(Wv[k * 128 + n]);
      } else {
        float s = 0.f;
        for (int e2 = 0; e2 < 128; e2++) s += Wv[k * 128 + e2] * W1[(128 + e2) * 128 + n];
        gvsw[f] = f2bf(s);
      }
    }
  } else if (t < 114816) {               // c1
    int c = t - 114688;
    float s = b1[c];
    for (int e2 = 0; e2 < 128; e2++)
      s += bp[e2] * W1[e2 * 128 + c] + bv[e2] * W1[(128 + e2) * 128 + c];
    c1[c] = s;
  }
}

// ---------------------------------------------------------------------------
// k1: projection GEMM. grid=512: b>>2 = 64-row chunk, b&3 = {side,half}.
// 2 blk/CU; FULL 32 KB B-frag table staged into LDS once per block.
// ---------------------------------------------------------------------------
__global__ __launch_bounds__(256, 2) void k1_proj(
    const float* __restrict__ price, const float* __restrict__ liquid,
    const float* __restrict__ bp, const float* __restrict__ bv, const float* __restrict__ c1,
    const unsigned short* __restrict__ wpsw, const unsigned short* __restrict__ gpsw,
    const unsigned short* __restrict__ wvsw, const unsigned short* __restrict__ gvsw,
    unsigned short* __restrict__ pbf, unsigned short* __restrict__ vbf,
    float* __restrict__ pAc, unsigned short* __restrict__ vbsw) {
  __shared__ __align__(16) unsigned short sA[64 * 136];   // 17.4 KB
  __shared__ __align__(16) unsigned short sB[16384];      // 32 KB (FULL table)
  int b = blockIdx.x;
  int chunk = b >> 2, sel = b & 3;
  int side = sel >> 1, half = sel & 1;
  int rowbase = chunk * 64;
  const float* src = side ? liquid : price;
  const unsigned short* bsw = side ? (half ? gvsw : wvsw) : (half ? gpsw : wpsw);
  int tid = threadIdx.x;

#pragma unroll
  for (int r = 0; r < 8; r++)             // stage B-frag table (32 KB)
    cp16(&sB[r * 2048 + tid * 8], bsw + r * 2048 + tid * 8);

#pragma unroll
  for (int i = 0; i < 8; i++) {           // stage A rows (64x128 f32 -> bf16)
    int e4 = i * 256 + tid;
    int row = e4 >> 5, c4 = (e4 & 31) * 4;
    float4 f = *(const float4*)(src + (rowbase + row) * 128 + c4);
    uint2 pk;
    pk.x = pk2(f.y, f.x);   // truncation is fine for GEMM inputs
    pk.y = pk2(f.w, f.z);
    *(uint2*)&sA[row * 136 + c4] = pk;
  }
  __syncthreads();

  int lane = tid & 63, w = tid >> 6;
  int l15 = lane & 15, q4 = lane >> 4;
  f32x4 acc[8] = {};
#pragma unroll
  for (int kt = 0; kt < 4; kt++) {
    short8 a0 = *(const short8*)&sA[(w * 16 + l15) * 136 + kt * 32 + q4 * 8];
#pragma unroll
    for (int ct = 0; ct < 8; ct++) {
      short8 bfr = *(const short8*)&sB[((ct * 4 + kt) * 64 + lane) * 8];
      acc[ct] = __builtin_amdgcn_mfma_f32_16x16x32_bf16(a0, bfr, acc[ct], 0, 0, 0);
    }
  }

#pragma unroll
  for (int ct = 0; ct < 8; ct++) {
    int col = ct * 16 + l15;
    int lrow0 = w * 16 + q4 * 4;
#pragma unroll
    for (int ri = 0; ri < 4; ri++) {
      int grow = rowbase + lrow0 + ri;
      float val = acc[ct][ri];
      if (side == 0) {
        if (half == 0) pbf[grow * 128 + col] = f2bf(val + bp[col]);
        else           pAc[grow * 128 + col] = val + c1[col];
      } else {
        if (half == 0) vbf[grow * 128 + col] = f2bf(val + bv[col]);
        else {
          int btl = grow >> 5, m = grow & 31;
          int idx = btl * 4096 +
                    ((((m >> 4) * 4 + (col >> 5)) * 64) + ((m >> 3) & 1) * 32 + (col & 31)) * 8 +
                    (m & 7);
          vbsw[idx] = f2bf(val);   // 32x32x16 B-frag order, K index = m
        }
      }
    }
  }
}

// ---------------------------------------------------------------------------
// k2_fused: pair stage + output GEMM. grid=2048. R9 + plain epilogue stores.
// ---------------------------------------------------------------------------
__global__ __launch_bounds__(256, 3) void k2_fused(
    const unsigned short* __restrict__ pbf, const unsigned short* __restrict__ vbf,
    const float* __restrict__ pAc, const unsigned short* __restrict__ w1cd,
    const unsigned short* __restrict__ vbsw, const unsigned short* __restrict__ w2sw,
    const float* __restrict__ b2, float* __restrict__ out) {
  __shared__ __align__(16) unsigned short sVf[4096];        // v in 32x32x16 A-frag order (8 KB)
  __shared__ __align__(16) unsigned short sP[4 * 136];      // p rows for this slab (1.1 KB)
  __shared__ __align__(16) unsigned short sHt[4][32 * 72];  // per-wave transpose buf (18.4 KB)
  __shared__ __align__(16) unsigned short sVb[4096];        // vbsw slab, B-frag order (8 KB)
  __shared__ __align__(16) unsigned short sT[8192];         // w1cd kt-slice dbuf 2x8KB (16 KB)
  int bt = blockIdx.x >> 3, slab = (blockIdx.x & 7) * 4;
  int tid = threadIdx.x;
  const unsigned short* vbswt = vbsw + bt * 4096;

  // async table stages: w1cd kt=0 slice (x half + y half) and vbsw slab
  cp16(&sT[tid * 8],        w1cd + tid * 8);                 // x, kt=0
  cp16(&sT[2048 + tid * 8], w1cd + 16384 + tid * 8);         // y, kt=0
  cp16(&sVb[tid * 8],        vbswt + tid * 8);
  cp16(&sVb[2048 + tid * 8], vbswt + 2048 + tid * 8);

  if (tid < 64) {  // stage p (4 rows)
    int row = tid >> 4, seg = tid & 15;
    *(uint4*)&sP[row * 136 + seg * 8] = *(const uint4*)(pbf + (bt * 32 + slab + row) * 128 + seg * 8);
  }
#pragma unroll
  for (int g2 = 0; g2 < 2; g2++) {  // stage v in A-frag order: ((kt*2+hi)*32+m)*8+j
    int g = tid * 2 + g2;
    int m = g & 31, k0 = (g >> 5) * 8;
    *(uint4*)&sVf[g * 8] = *(const uint4*)(vbf + (bt * 32 + m) * 128 + k0);
  }
  __syncthreads();

  int lane = tid & 63, w = tid >> 6;
  int m31 = lane & 31, hi = lane >> 5;
  int n = slab + w;                 // this wave's n row

  // per-lane constants: pAc row (per ct col-block), b2 bias
  float pa[4], bia[4];
#pragma unroll
  for (int ct = 0; ct < 4; ct++) {
    pa[ct]  = pAc[(bt * 32 + n) * 128 + ct * 32 + m31];
    bia[ct] = b2[ct * 32 + m31];
  }

  f32x16 acc[4] = {};

#pragma unroll
  for (int kt = 0; kt < 8; kt++) {  // K=128 over x=(p*v) and y=|p-v| together
    const unsigned short* bcur = sT + (kt & 1) * 4096;
    if (kt < 7) {                   // 2-phase: issue next kt slice while computing
      unsigned short* bnx = sT + ((kt + 1) & 1) * 4096;
      cp16(&bnx[tid * 8],        w1cd + (kt + 1) * 2048 + tid * 8);
      cp16(&bnx[2048 + tid * 8], w1cd + (kt + 9) * 2048 + tid * 8);
    }
    V8 vf, pp, x, y;
    vf.u = *(const uint4*)&sVf[((kt * 2 + hi) * 32 + m31) * 8];
    pp.u = *(const uint4*)&sP[w * 136 + kt * 16 + hi * 8];
#pragma unroll
    for (int i = 0; i < 4; i++) {
      float vl = lo16(vf.a[i]), vh = hi16(vf.a[i]);
      float al = lo16(pp.a[i]), ah = hi16(pp.a[i]);
      x.a[i] = pk2(ah * vh, al * vl);
      y.a[i] = pk2(fabsf(ah - vh), fabsf(al - vl));
    }
#pragma unroll
    for (int ct = 0; ct < 4; ct++) {
      short8 bx = *(const short8*)(bcur + ct * 512 + lane * 8);
      short8 by = *(const short8*)(bcur + 2048 + ct * 512 + lane * 8);
      acc[ct] = __builtin_amdgcn_mfma_f32_32x32x16_bf16(x.s, bx, acc[ct], 0, 0, 0);
      acc[ct] = __builtin_amdgcn_mfma_f32_32x32x16_bf16(y.s, by, acc[ct], 0, 0, 0);
    }
    __syncthreads();                // stage kt+1 done; all waves done with bcur
  }

  // stage w2 p0 slice (16 KB) into the now-dead sT
#pragma unroll
  for (int r = 0; r < 4; r++)
    cp16(&sT[r * 2048 + tid * 8], w2sw + r * 2048 + tid * 8);

  // vB via indicator GEMM: A[r][k]=delta(r==k), B=vB (frag order), K=32
#pragma unroll
  for (int kt2 = 0; kt2 < 2; kt2++) {
    short8 indf;
#pragma unroll
    for (int j = 0; j < 8; j++)
      indf[j] = (short)(((kt2 * 16 + hi * 8 + j) == m31) ? 0x3F80 : 0);
#pragma unroll
    for (int ct = 0; ct < 4; ct++) {
      short8 bi = *(const short8*)(sVb + (kt2 * 4 + ct) * 512 + lane * 8);
      acc[ct] = __builtin_amdgcn_mfma_f32_32x32x16_bf16(indf, bi, acc[ct], 0, 0, 0);
    }
  }
  __syncthreads();                  // w2 p0 stage complete

  // silu (pAc folded) -> 2-pass LDS transpose (32x72, per-wave) -> h@W2+b2
  unsigned short* sh = &sHt[w][0];
  f32x16 o[4] = {};
#pragma unroll
  for (int p = 0; p < 2; p++) {
    if (p == 0) {                   // stage w2 p1 slice into dead sVf+sVb
#pragma unroll
      for (int r = 0; r < 4; r++)
        cp16(r < 2 ? &sVf[r * 2048 + tid * 8] : &sVb[(r - 2) * 2048 + tid * 8],
             w2sw + 8192 + r * 2048 + tid * 8);
    }
#pragma unroll
    for (int c2 = 0; c2 < 2; c2++) {
      int ct = p * 2 + c2;
#pragma unroll
      for (int reg = 0; reg < 16; reg++) {
        float z = acc[ct][reg] + pa[ct];
        float hv = z * __builtin_amdgcn_rcpf(1.f + __expf(-z));
        int mr = (reg & 3) + 8 * (reg >> 2) + 4 * hi;   // C-layout row = pair m
        sh[mr * 72 + c2 * 32 + m31] = (unsigned short)(__float_as_uint(hv) >> 16);
      }
    }
#pragma unroll
    for (int kt = 0; kt < 4; kt++) {
      short8 hf = *(const short8*)&sh[m31 * 72 + kt * 16 + hi * 8];
#pragma unroll
      for (int ct2 = 0; ct2 < 4; ct2++) {
        int idx = (kt * 4 + ct2) * 512 + lane * 8;      // shorts, within 16KB slice
        const unsigned short* wsrc;
        if (p == 0)       wsrc = sT + idx;
        else if (kt < 2)  wsrc = sVf + idx;
        else              wsrc = sVb + idx - 4096;
        short8 wf = *(const short8*)wsrc;
        o[ct2] = __builtin_amdgcn_mfma_f32_32x32x16_bf16(hf, wf, o[ct2], 0, 0, 0);
      }
    }
    if (p == 0) __syncthreads();    // w2 p1 stage complete before p=1 reads
  }

  int rowb = bt * 1024 + n * 32;
#pragma unroll
  for (int ct2 = 0; ct2 < 4; ct2++) {
#pragma unroll
    for (int reg = 0; reg < 16; reg++) {
      int mr = (reg & 3) + 8 * (reg >> 2) + 4 * hi;
      out[(rowb + mr) * 128 + ct2 * 32 + m31] = o[ct2][reg] + bia[ct2];
    }
  }
}

// ---------------------------------------------------------------------------
extern "C" void kernel_launch(void* const* d_in, const int* in_sizes, int n_in,
                              void* d_out, int out_size, void* d_ws, size_t ws_size,
                              hipStream_t stream) {
  const float* price  = (const float*)d_in[0];
  const float* liquid = (const float*)d_in[1];
  const float* Wp     = (const float*)d_in[2];
  const float* bp     = (const float*)d_in[3];
  const float* Wv     = (const float*)d_in[4];
  const float* bv     = (const float*)d_in[5];
  const float* W1     = (const float*)d_in[6];
  const float* b1     = (const float*)d_in[7];
  const float* W2     = (const float*)d_in[8];
  const float* b2     = (const float*)d_in[9];

  char* ws = (char*)d_ws;
  unsigned short* w1cd = (unsigned short*)(ws + 0);         //  64 KB
  unsigned short* w2sw = (unsigned short*)(ws + 65536);     //  32 KB
  unsigned short* wpsw = (unsigned short*)(ws + 98304);     //  32 KB
  unsigned short* gpsw = (unsigned short*)(ws + 131072);    //  32 KB
  unsigned short* wvsw = (unsigned short*)(ws + 163840);    //  32 KB
  unsigned short* gvsw = (unsigned short*)(ws + 196608);    //  32 KB
  float*          c1   = (float*)(ws + 229376);             // 512 B
  unsigned short* pbf  = (unsigned short*)(ws + 262144);    //   2 MB
  unsigned short* vbf  = (unsigned short*)(ws + 2359296);   //   2 MB
  float*          pAc  = (float*)(ws + 4456448);            //   4 MB
  unsigned short* vbsw = (unsigned short*)(ws + 8650752);   //   2 MB -> total ~10.3 MB

  hipLaunchKernelGGL(k0_prep, dim3(449), dim3(256), 0, stream,
                     Wp, bp, Wv, bv, W1, b1, W2, w1cd, w2sw, wpsw, gpsw, wvsw, gvsw, c1);
  hipLaunchKernelGGL(k1_proj, dim3(512), dim3(256), 0, stream,
                     price, liquid, bp, bv, c1, wpsw, gpsw, wvsw, gvsw, pbf, vbf, pAc, vbsw);
  hipLaunchKernelGGL(k2_fused, dim3(2048), dim3(256), 0, stream,
                     pbf, vbf, pAc, w1cd, vbsw, w2sw, b2, (float*)d_out);
}